// Round 11
// baseline (379.521 us; speedup 1.0000x reference)
//
#include <hip/hip_runtime.h>
#include <math.h>

#define KSLOTS 8
#define PN     131072
#define LOC_RATIO 0.5714285714285714f
#define INV2048 4.8828125e-4f
#define RPS    70     // A-plane row-pair stride (dwords): 70≡6 mod 32 -> b128 read bank-starts 2-way (free);
                      // 68≡4 was 4-way on reads. Writes go 2-way -> ~3-way (minor). 8B-aligned odd rows =
                      // same alignment class as the 10-rounds-green QST=42 Q reads.
#define QST    42     // Q-plane row-pair stride

typedef _Float16 f16x8 __attribute__((ext_vector_type(8)));
typedef __fp16 pk16x2 __attribute__((ext_vector_type(2)));
typedef float floatx4 __attribute__((ext_vector_type(4)));
union F4H8 { int4 i; f16x8 h; };
union PK2I { pk16x2 h; int i; };

#define MFMA(A_,B_,C_) __builtin_amdgcn_mfma_f32_16x16x32_f16(A_,B_,C_,0,0,0)

// ---- B-fragment pair bases ----
#define EB_B0   0
#define EB_B1   4
#define EB_B2   12
#define EB_A0Q  20
#define EB_A0H  24
#define EB_A1   32
#define EB_A2   40
#define EB_LAT  48
#define EB_C0   58
#define WS_ZB0  30720
#define WS_ZA0  31232
#define WS_BST  31744   // b1@0 b2@64 a1@128 a2@192 latsh@256(80) c0@336(16)
#define WS_W32  32096

// ---- output layout (float offsets) ----
#define OFF_RAWS     0
#define OFF_MASKED   524288
#define OFF_UNMASK   4718592
#define OFF_MASKS    8912896

// ---- per-wave LDS map (dwords), RPS=70 planes (560 dw each) ----
// AH0 [0,560), AH1 [560,1120); QH0 overlays AH0 head, QH1 overlays AH1 head.
// CC dedicated [1120,1760). scratch at tail. 7424 B/wave, 14848 B/block.
#define L_AH0  0
#define L_AH1  560
#define L_CC0  1120
#define L_CC1  1440
#define L_Q32  1760
#define L_OUTS 1792
#define L_SIG  1824
#define LROW   1856

// ============================ prep kernel ============================
__global__ void prep_kernel(const float* __restrict__ z_slots,
                            const float* __restrict__ w_b0, const float* __restrict__ b_b0,
                            const float* __restrict__ w_b1, const float* __restrict__ b_b1,
                            const float* __restrict__ w_b2, const float* __restrict__ b_b2,
                            const float* __restrict__ w_a0, const float* __restrict__ b_a0,
                            const float* __restrict__ w_a1, const float* __restrict__ b_a1,
                            const float* __restrict__ w_a2, const float* __restrict__ b_a2,
                            const float* __restrict__ w_lat, const float* __restrict__ b_lat,
                            const float* __restrict__ w_sh, const float* __restrict__ b_sh,
                            const float* __restrict__ w_c0, const float* __restrict__ b_c0,
                            float* __restrict__ ws) {
    const int tid = blockIdx.x * blockDim.x + threadIdx.x;
    if (tid < 7680) {
        const int lane = tid & 63;
        const int term = (tid >> 6) & 1;
        const int e    = tid >> 7;         // 0..59
        int u, nt, ks;
        if      (e < 4)  { u = 0; nt = e;            ks = 0; }
        else if (e < 12) { u = 1; nt = (e-4)  >> 1;  ks = (e-4)  & 1; }
        else if (e < 20) { u = 2; nt = (e-12) >> 1;  ks = (e-12) & 1; }
        else if (e < 24) { u = 3; nt = e - 20;       ks = 0; }
        else if (e < 32) { u = 4; nt = (e-24) >> 1;  ks = (e-24) & 1; }
        else if (e < 40) { u = 5; nt = (e-32) >> 1;  ks = (e-32) & 1; }
        else if (e < 48) { u = 6; nt = (e-40) >> 1;  ks = (e-40) & 1; }
        else if (e < 58) { u = 7; nt = (e-48) >> 1;  ks = (e-48) & 1; }
        else             { u = 8; nt = 0;            ks = e - 58; }
        const int jo = nt * 16 + (lane & 15);
        const int quad = lane >> 4;
        f16x8 frag;
#pragma unroll
        for (int j = 0; j < 8; ++j) {
            const int k = ks * 32 + quad * 8 + j;
            float w = 0.0f;
            switch (u) {
                case 0: w = w_b0[jo * 97 + k]; break;
                case 1: w = w_b1[jo * 64 + k]; break;
                case 2: w = w_b2[jo * 64 + k]; break;
                case 3: w = w_a0[jo * 161 + k]; break;
                case 4: w = w_a0[jo * 161 + 97 + k]; break;
                case 5: w = w_a1[jo * 64 + k]; break;
                case 6: w = w_a2[jo * 64 + k]; break;
                case 7: w = (jo < 64) ? w_lat[jo * 64 + k]
                          : ((jo == 64) ? w_sh[k] : 0.0f); break;
                default: w = w_c0[jo * 64 + k]; break;
            }
            const _Float16 hi = (_Float16)w;
            frag[j] = (term == 0) ? hi : (_Float16)((w - (float)hi) * 2048.0f);
        }
        ((f16x8*)ws)[tid] = frag;
    } else if (tid < 8192) {
        const int idx = tid - 7680;
        const int k = idx >> 6, j = idx & 63;
        float s0 = b_b0[j], s1 = b_a0[j];
        for (int i = 0; i < 64; ++i) {
            const float zv = z_slots[k * 64 + i];
            s0 = fmaf(w_b0[j * 97 + 33 + i], zv, s0);
            s1 = fmaf(w_a0[j * 161 + 33 + i], zv, s1);
        }
        ws[WS_ZB0 + idx] = s0;
        ws[WS_ZA0 + idx] = s1;
    } else if (tid < 8544) {
        const int idx = tid - 8192;
        float v;
        if      (idx < 64)  v = b_b1[idx];
        else if (idx < 128) v = b_b2[idx - 64];
        else if (idx < 192) v = b_a1[idx - 128];
        else if (idx < 256) v = b_a2[idx - 192];
        else if (idx < 336) { const int j = idx - 256; v = (j < 64) ? b_lat[j] : ((j == 64) ? b_sh[0] : 0.0f); }
        else                v = b_c0[idx - 336];
        ws[WS_BST + idx] = v;
    } else if (tid < 8672) {
        const int idx = tid - 8544;
        const int j = idx & 63;
        ws[WS_W32 + idx] = (idx < 64) ? w_b0[j * 97 + 32] : w_a0[j * 161 + 32];
    }
}

// ============================ device helpers ============================
__device__ __forceinline__ f16x8 rdfrag(const int* plane, int addr, unsigned sel) {
    const int4 a = *(const int4*)(plane + addr);
    const int4 b = *(const int4*)(plane + addr + 4);
    F4H8 u;
    u.i.x = __builtin_amdgcn_perm(a.y, a.x, sel);
    u.i.y = __builtin_amdgcn_perm(a.w, a.z, sel);
    u.i.z = __builtin_amdgcn_perm(b.y, b.x, sel);
    u.i.w = __builtin_amdgcn_perm(b.w, b.z, sel);
    return u.h;
}

__device__ __forceinline__ f16x8 as_h8(int4 v) { F4H8 u; u.i = v; return u.h; }

__device__ __forceinline__ int pkrtz_i(float a, float b) {
    PK2I u;
    u.h = __builtin_amdgcn_cvt_pkrtz(a, b);
    return u.i;
}

__device__ __forceinline__ void st_hi(int* AHw, int addr, floatx4 v) {
    AHw[addr]       = pkrtz_i(v[0], v[1]);
    AHw[addr + RPS] = pkrtz_i(v[2], v[3]);
}

// hi-only Q store
__device__ __forceinline__ void st_h16(int* QHw, int rp, int halfsel, int feat, float v) {
    ((unsigned short*)QHw)[(rp * QST + feat) * 2 + halfsel] =
        __builtin_bit_cast(unsigned short, (_Float16)v);
}

// dual-tile 64->64 hidden unit, HI-ONLY precision
__device__ __forceinline__ void unitHiDual(int* AH0, int* AH1,
                                           const int4* Bp, int ebase,
                                           const float* __restrict__ bias,
                                           f16x8 th0, f16x8 th1, f16x8 uh0, f16x8 uh1,
                                           int lane, int n, int wrA) {
    int4 B[8];
    floatx4 ac0[4], ac1[4];
#pragma unroll
    for (int nt = 0; nt < 4; ++nt) {
        B[nt*2+0] = Bp[((ebase + nt*2)*2 + 0) * 64 + lane];   // k0 hi
        B[nt*2+1] = Bp[((ebase + nt*2)*2 + 2) * 64 + lane];   // k1 hi
    }
    __builtin_amdgcn_s_setprio(1);
#pragma unroll
    for (int nt = 0; nt < 4; ++nt) {
        const float bv = bias[nt * 16 + n];
        const f16x8 bh0 = as_h8(B[nt*2+0]), bh1 = as_h8(B[nt*2+1]);
        ac0[nt] = (floatx4){bv, bv, bv, bv};
        ac1[nt] = (floatx4){bv, bv, bv, bv};
        ac0[nt] = MFMA(th0, bh0, ac0[nt]); ac0[nt] = MFMA(th1, bh1, ac0[nt]);
        ac1[nt] = MFMA(uh0, bh0, ac1[nt]); ac1[nt] = MFMA(uh1, bh1, ac1[nt]);
    }
    __builtin_amdgcn_s_setprio(0);
#pragma unroll
    for (int nt = 0; nt < 4; ++nt) {
        floatx4 v0, v1;
#pragma unroll
        for (int r = 0; r < 4; ++r) {
            v0[r] = fmaxf(ac0[nt][r], 0.0f);
            v1[r] = fmaxf(ac1[nt][r], 0.0f);
        }
        st_hi(AH0, wrA + nt * 16, v0);
        st_hi(AH1, wrA + nt * 16, v1);
    }
}

// ============================ main kernel ============================
__global__ __launch_bounds__(128, 3)
void fg_kernel(const float* __restrict__ coor_in,
               const float* __restrict__ fg_transform,
               const float* __restrict__ fg_slot_pos,
               const float* __restrict__ w_c1, const float* __restrict__ b_c1,
               const float* __restrict__ ws,
               float* __restrict__ out) {
    __shared__ int LB[2][LROW];
    const int lane = threadIdx.x & 63;
    const int wv   = threadIdx.x >> 6;
    const int tile = blockIdx.x * 2 + wv;     // 32 points per wave (2 tiles of 16)
    const int kk = tile >> 12;                // 4096 tiles per slot
    const int p0 = (tile & 4095) << 5;

    int* AH0 = LB[wv] + L_AH0;
    int* AH1 = LB[wv] + L_AH1;
    float* Q32w  = (float*)(LB[wv] + L_Q32);
    float* OUTSw = (float*)(LB[wv] + L_OUTS);
    float* SIGw  = (float*)(LB[wv] + L_SIG);
    float* CC0   = (float*)(LB[wv] + L_CC0);
    float* CC1   = (float*)(LB[wv] + L_CC1);

    const int* ws_i = (const int*)ws;
    const int4* Bp = (const int4*)ws_i;
    const int n = lane & 15, quad = lane >> 4;
    const unsigned sel = (n & 1) ? 0x07060302u : 0x05040100u;
    const int rdA = (n >> 1) * RPS + quad * 8;
    const int rdQ = (n >> 1) * QST + quad * 8;
    const int wrA = (2 * quad) * RPS + n;

    // ---- phase 0: embedding for both tiles (role = quad, point = n), hi-only Q ----
    // QH planes overlay the heads of AH0/AH1 (Q dies when b0 writes A).
#pragma unroll
    for (int t = 0; t < 2; ++t) {
        int* QHt = LB[wv] + t * 560;
        const int p = n;
        const int role = quad;
        const long idx3 = ((long)kk * PN + p0 + t * 16 + p) * 3;
        const float x = coor_in[idx3 + 0];
        const float y = coor_in[idx3 + 1];
        const float zc = coor_in[idx3 + 2];
        const float T00 = fg_transform[0], T01 = fg_transform[1], T02 = fg_transform[2];
        const float T10 = fg_transform[3], T11 = fg_transform[4], T12 = fg_transform[5];
        const float T20 = fg_transform[6], T21 = fg_transform[7], T22 = fg_transform[8];
        if (role < 3) {
            const float px = fg_slot_pos[kk*3+0], py = fg_slot_pos[kk*3+1], pz = fg_slot_pos[kk*3+2];
            const float rx = x - px, ry = y - py, rz = zc - pz;
            const float cx = T00*rx + T01*ry + T02*rz;
            const float cy = T10*rx + T11*ry + T12*rz;
            const float cz = T20*rx + T21*ry + T22*rz;
            const float c = (role == 0) ? cx : ((role == 1) ? cy : cz);
            const int rp = p >> 1;
            const int hs = p & 1;
            st_h16(QHt, rp, hs, role, c);
            const float rev = c * 0.15915494309189535f;
            const float fr = rev - floorf(rev);
            float s  = __builtin_amdgcn_sinf(fr);
            float co = __builtin_amdgcn_cosf(fr);
#pragma unroll
            for (int l = 0; l < 5; ++l) {
                st_h16(QHt, rp, hs, 3 + 6*l + role, s);
                if (l == 4 && role == 2) {
                    Q32w[t * 16 + p] = co;
                } else {
                    st_h16(QHt, rp, hs, 6 + 6*l + role, co);
                }
                if (l < 4) {
                    const float tt = s * co;
                    const float s2 = s * s;
                    co = fmaf(-2.0f, s2, 1.0f);
                    s  = tt + tt;
                }
            }
        } else {
            const float o0 = T00*x + T01*y + T02*zc;
            const float o1 = T10*x + T11*y + T12*zc;
            const float o2 = T20*x + T21*y + T22*zc;
            const bool outs = (fabsf(o0) > LOC_RATIO) || (fabsf(o1) > LOC_RATIO) || (fabsf(o2) > LOC_RATIO);
            OUTSw[t * 16 + p] = outs ? 1.0f : 0.0f;
        }
    }

    // ---- q hi fragments for both tiles -> registers ----
    const f16x8 qh_0 = rdfrag(LB[wv] + 0,   rdQ, sel);
    const f16x8 qh_1 = rdfrag(LB[wv] + 560, rdQ, sel);

    // ---- b0: q(K=32) hi-only + rank-1 q32; hi-only output ----
    {
        const float* zb0 = ws + WS_ZB0 + kk * 64;
        const float* w32p = ws + WS_W32;
        int4 B[4];
#pragma unroll
        for (int nt = 0; nt < 4; ++nt) {
            B[nt] = Bp[((EB_B0 + nt)*2 + 0) * 64 + lane];
        }
#pragma unroll
        for (int nt = 0; nt < 4; ++nt) {
            const float bv = zb0[nt * 16 + n];
            const float w32 = w32p[nt * 16 + n];
            const f16x8 bh = as_h8(B[nt]);
            floatx4 ac0 = {bv, bv, bv, bv};
            floatx4 ac1 = {bv, bv, bv, bv};
            __builtin_amdgcn_s_setprio(1);
            ac0 = MFMA(qh_0, bh, ac0);
            ac1 = MFMA(qh_1, bh, ac1);
            __builtin_amdgcn_s_setprio(0);
            floatx4 v0, v1;
#pragma unroll
            for (int r = 0; r < 4; ++r) {
                v0[r] = fmaxf(fmaf(w32, Q32w[quad*4+r],    ac0[r]), 0.0f);
                v1[r] = fmaxf(fmaf(w32, Q32w[16+quad*4+r], ac1[r]), 0.0f);
            }
            st_hi(AH0, wrA + nt * 16, v0);
            st_hi(AH1, wrA + nt * 16, v1);
        }
    }

    f16x8 th0, th1, uh0, uh1;
#define RD_H() do { \
        th0 = rdfrag(AH0, rdA, sel);      th1 = rdfrag(AH0, rdA + 32, sel); \
        uh0 = rdfrag(AH1, rdA, sel);      uh1 = rdfrag(AH1, rdA + 32, sel); \
    } while (0)

    RD_H(); unitHiDual(AH0, AH1, Bp, EB_B1, ws + WS_BST + 0,   th0, th1, uh0, uh1, lane, n, wrA);
    RD_H(); unitHiDual(AH0, AH1, Bp, EB_B2, ws + WS_BST + 64,  th0, th1, uh0, uh1, lane, n, wrA);

    // ---- a0: q-part (K=32) hi-only + h-part (K=64) hi-only + rank-1 ----
    RD_H();
    {
        const float* za0 = ws + WS_ZA0 + kk * 64;
        const float* w32p = ws + WS_W32 + 64;
        floatx4 ac0[4], ac1[4];
        int4 B[8];
#pragma unroll
        for (int nt = 0; nt < 4; ++nt) {
            B[nt] = Bp[((EB_A0Q + nt)*2 + 0) * 64 + lane];
        }
        __builtin_amdgcn_s_setprio(1);
#pragma unroll
        for (int nt = 0; nt < 4; ++nt) {
            const float bv = za0[nt * 16 + n];
            const f16x8 bh = as_h8(B[nt]);
            ac0[nt] = (floatx4){bv, bv, bv, bv};
            ac1[nt] = (floatx4){bv, bv, bv, bv};
            ac0[nt] = MFMA(qh_0, bh, ac0[nt]);
            ac1[nt] = MFMA(qh_1, bh, ac1[nt]);
        }
        __builtin_amdgcn_s_setprio(0);
        // h-part: hi-only weights (k0 and k1 hi frags)
#pragma unroll
        for (int nt = 0; nt < 4; ++nt) {
            B[nt*2+0] = Bp[((EB_A0H + nt*2)*2 + 0) * 64 + lane];   // k0 hi
            B[nt*2+1] = Bp[((EB_A0H + nt*2)*2 + 2) * 64 + lane];   // k1 hi
        }
        __builtin_amdgcn_s_setprio(1);
#pragma unroll
        for (int nt = 0; nt < 4; ++nt) {
            const f16x8 bh0 = as_h8(B[nt*2+0]), bh1 = as_h8(B[nt*2+1]);
            ac0[nt] = MFMA(th0, bh0, ac0[nt]); ac0[nt] = MFMA(th1, bh1, ac0[nt]);
            ac1[nt] = MFMA(uh0, bh0, ac1[nt]); ac1[nt] = MFMA(uh1, bh1, ac1[nt]);
        }
        __builtin_amdgcn_s_setprio(0);
#pragma unroll
        for (int nt = 0; nt < 4; ++nt) {
            const float w32 = w32p[nt * 16 + n];
            floatx4 v0, v1;
#pragma unroll
            for (int r = 0; r < 4; ++r) {
                v0[r] = fmaxf(fmaf(w32, Q32w[quad*4+r],    ac0[nt][r]), 0.0f);
                v1[r] = fmaxf(fmaf(w32, Q32w[16+quad*4+r], ac1[nt][r]), 0.0f);
            }
            st_hi(AH0, wrA + nt * 16, v0);
            st_hi(AH1, wrA + nt * 16, v1);
        }
    }

    RD_H(); unitHiDual(AH0, AH1, Bp, EB_A1, ws + WS_BST + 128, th0, th1, uh0, uh1, lane, n, wrA);
    RD_H(); unitHiDual(AH0, AH1, Bp, EB_A2, ws + WS_BST + 192, th0, th1, uh0, uh1, lane, n, wrA);

    // ---- lat (hi-only, no relu) + shape (hi-only -> SIG) ----
    RD_H();
    {
        const float* bias = ws + WS_BST + 256;   // latsh[80]
        int4 B[8];
#pragma unroll
        for (int nt = 0; nt < 4; ++nt) {
            B[nt*2+0] = Bp[((EB_LAT + nt*2)*2 + 0) * 64 + lane];
            B[nt*2+1] = Bp[((EB_LAT + nt*2)*2 + 2) * 64 + lane];
        }
        __builtin_amdgcn_s_setprio(1);
#pragma unroll
        for (int nt = 0; nt < 4; ++nt) {
            const float bv = bias[nt * 16 + n];
            const f16x8 bh0 = as_h8(B[nt*2+0]), bh1 = as_h8(B[nt*2+1]);
            floatx4 a0 = {bv, bv, bv, bv}, a1 = {bv, bv, bv, bv};
            a0 = MFMA(th0, bh0, a0); a0 = MFMA(th1, bh1, a0);
            a1 = MFMA(uh0, bh0, a1); a1 = MFMA(uh1, bh1, a1);
            st_hi(AH0, wrA + nt * 16, a0);
            st_hi(AH1, wrA + nt * 16, a1);
        }
        __builtin_amdgcn_s_setprio(0);
        // shape (sigma) — hi activations, hi weights
        {
            const float bv = bias[64 + n];
            const int e0 = EB_LAT + 8;
            const f16x8 bh0 = as_h8(Bp[(e0*2+0) * 64 + lane]);
            const f16x8 bh1 = as_h8(Bp[(e0*2+2) * 64 + lane]);
            floatx4 a0 = {bv, bv, bv, bv};
            floatx4 a1 = {bv, bv, bv, bv};
            __builtin_amdgcn_s_setprio(1);
            a0 = MFMA(th0, bh0, a0); a0 = MFMA(th1, bh1, a0);
            a1 = MFMA(uh0, bh0, a1); a1 = MFMA(uh1, bh1, a1);
            __builtin_amdgcn_s_setprio(0);
            if (n == 0) {
#pragma unroll
                for (int r = 0; r < 4; ++r) {
                    SIGw[quad * 4 + r]      = a0[r];
                    SIGw[16 + quad * 4 + r] = a1[r];
                }
            }
        }
    }

    // ---- c0: 64 -> 16, hi-only, relu; CC in dedicated region ----
    RD_H();
    {
        const float* bias = ws + WS_BST + 336;
        const float bv = bias[n];
        const f16x8 bh0 = as_h8(Bp[((EB_C0+0)*2+0) * 64 + lane]);
        const f16x8 bh1 = as_h8(Bp[((EB_C0+1)*2+0) * 64 + lane]);
        floatx4 a0 = {bv, bv, bv, bv}, a1 = {bv, bv, bv, bv};
        a0 = MFMA(th0, bh0, a0); a0 = MFMA(th1, bh1, a0);
        a1 = MFMA(uh0, bh0, a1); a1 = MFMA(uh1, bh1, a1);
#pragma unroll
        for (int r = 0; r < 4; ++r) {
            CC0[(quad * 4 + r) * 20 + n] = fmaxf(a0[r], 0.0f);
            CC1[(quad * 4 + r) * 20 + n] = fmaxf(a1[r], 0.0f);
        }
    }

    // ---- heads: lane = p*4 + o, both tiles ----
#pragma unroll
    for (int t = 0; t < 2; ++t) {
        const float* CCt = t ? CC1 : CC0;
        const int p = lane >> 2, o = lane & 3;
        float v;
        if (o < 3) {
            const float* cr = CCt + p * 20;
            float a = b_c1[o];
#pragma unroll
            for (int i = 0; i < 16; ++i) a = fmaf(w_c1[o * 16 + i], cr[i], a);
            // (tanh(a)+1)/2 == sigmoid(2a); native exp+rcp, ~1e-6 abs err vs 2e-2 thr
            const float e = __expf(-2.0f * a);
            v = __builtin_amdgcn_rcpf(1.0f + e);
        } else {
            const float sig = SIGw[t * 16 + p];
            const float outs = OUTSw[t * 16 + p];
            v = (outs > 0.5f) ? 0.0f : fmaxf(sig, 0.0f);
        }
        const long idx = (long)kk * PN + p0 + t * 16 + p;
        out[OFF_UNMASK + (idx << 2) + o] = v;
    }
#undef RD_H
}

// ============================ compose pass ============================
__global__ __launch_bounds__(256)
void compose_kernel(float* __restrict__ out) {
    const int p = blockIdx.x * blockDim.x + threadIdx.x;
    const float4* un = (const float4*)(out + OFF_UNMASK);
    float4 u[KSLOTS];
    float s = 0.0f;
#pragma unroll
    for (int k = 0; k < KSLOTS; ++k) {
        u[k] = un[k * PN + p];
        s += u[k].w;
    }
    // one IEEE division instead of 8 (x*(1/d) vs x/d differs by <=1 ulp; thr 2e-2)
    const float inv = 1.0f / (s + 1e-5f);
    float4* mk = (float4*)(out + OFF_MASKED);
    float* ms = out + OFF_MASKS;
    float4 r = make_float4(0.f, 0.f, 0.f, 0.f);
#pragma unroll
    for (int k = 0; k < KSLOTS; ++k) {
        const float m = u[k].w * inv;
        ms[k * PN + p] = m;
        const float4 v = make_float4(u[k].x * m, u[k].y * m, u[k].z * m, u[k].w * m);
        mk[k * PN + p] = v;
        r.x += v.x; r.y += v.y; r.z += v.z; r.w += v.w;
    }
    ((float4*)(out + OFF_RAWS))[p] = r;
}

// ============================ launch ============================
extern "C" void kernel_launch(void* const* d_in, const int* in_sizes, int n_in,
                              void* d_out, int out_size, void* d_ws, size_t ws_size,
                              hipStream_t stream) {
    const float* coor = (const float*)d_in[0];
    const float* z    = (const float*)d_in[1];
    const float* ft   = (const float*)d_in[2];
    const float* pos  = (const float*)d_in[3];
    const float* w_b0 = (const float*)d_in[4];  const float* b_b0 = (const float*)d_in[5];
    const float* w_b1 = (const float*)d_in[6];  const float* b_b1 = (const float*)d_in[7];
    const float* w_b2 = (const float*)d_in[8];  const float* b_b2 = (const float*)d_in[9];
    const float* w_a0 = (const float*)d_in[10]; const float* b_a0 = (const float*)d_in[11];
    const float* w_a1 = (const float*)d_in[12]; const float* b_a1 = (const float*)d_in[13];
    const float* w_a2 = (const float*)d_in[14]; const float* b_a2 = (const float*)d_in[15];
    const float* w_lat = (const float*)d_in[16]; const float* b_lat = (const float*)d_in[17];
    const float* w_sh  = (const float*)d_in[18]; const float* b_sh  = (const float*)d_in[19];
    const float* w_c0  = (const float*)d_in[20]; const float* b_c0  = (const float*)d_in[21];
    const float* w_c1  = (const float*)d_in[22]; const float* b_c1  = (const float*)d_in[23];
    float* out = (float*)d_out;
    float* ws  = (float*)d_ws;

    hipLaunchKernelGGL(prep_kernel, dim3(34), dim3(256), 0, stream,
                       z,
                       w_b0, b_b0, w_b1, b_b1, w_b2, b_b2,
                       w_a0, b_a0, w_a1, b_a1, w_a2, b_a2,
                       w_lat, b_lat, w_sh, b_sh, w_c0, b_c0, ws);
    hipLaunchKernelGGL(fg_kernel, dim3((KSLOTS * PN / 32) / 2), dim3(128), 0, stream,
                       coor, ft, pos, w_c1, b_c1, ws, out);
    hipLaunchKernelGGL(compose_kernel, dim3(PN / 256), dim3(256), 0, stream, out);
}

// Round 12
// 231.754 us; speedup vs baseline: 1.6376x; 1.6376x over previous
//
#include <hip/hip_runtime.h>
#include <math.h>

#define KSLOTS 8
#define PN     131072
#define LOC_RATIO 0.5714285714285714f
#define INV2048 4.8828125e-4f
#define RPS    68     // A-plane row-pair stride (dwords). MUST stay ≡0 mod 4: 16B-aligned ds_read_b128
                      // (round 11: RPS=70 halved conflicts but split the b128s -> fg 128->270 µs).
#define QST    42     // Q-plane row-pair stride

typedef _Float16 f16x8 __attribute__((ext_vector_type(8)));
typedef __fp16 pk16x2 __attribute__((ext_vector_type(2)));
typedef float floatx4 __attribute__((ext_vector_type(4)));
union F4H8 { int4 i; f16x8 h; };
union PK2I { pk16x2 h; int i; };

#define MFMA(A_,B_,C_) __builtin_amdgcn_mfma_f32_16x16x32_f16(A_,B_,C_,0,0,0)

// ---- B-fragment pair bases ----
#define EB_B0   0
#define EB_B1   4
#define EB_B2   12
#define EB_A0Q  20
#define EB_A0H  24
#define EB_A1   32
#define EB_A2   40
#define EB_LAT  48
#define EB_C0   58
#define WS_ZB0  30720
#define WS_ZA0  31232
#define WS_BST  31744   // b1@0 b2@64 a1@128 a2@192 latsh@256(80) c0@336(16)
#define WS_W32  32096

// ---- output layout (float offsets) ----
#define OFF_RAWS     0
#define OFF_MASKED   524288
#define OFF_UNMASK   4718592
#define OFF_MASKS    8912896

// ---- per-wave LDS map (dwords) ----
// AH0 [0,544), AH1 [544,1088); QH0/QH1 overlay the plane heads (Q dies at b0).
// CC dedicated [1088,1728). scratch at tail. 7296 B/wave, 14592 B/block.
#define L_AH0  0
#define L_AH1  544
#define L_CC0  1088
#define L_CC1  1408
#define L_Q32  1728
#define L_OUTS 1760
#define L_SIG  1792
#define LROW   1824

// ============================ prep kernel ============================
__global__ void prep_kernel(const float* __restrict__ z_slots,
                            const float* __restrict__ w_b0, const float* __restrict__ b_b0,
                            const float* __restrict__ w_b1, const float* __restrict__ b_b1,
                            const float* __restrict__ w_b2, const float* __restrict__ b_b2,
                            const float* __restrict__ w_a0, const float* __restrict__ b_a0,
                            const float* __restrict__ w_a1, const float* __restrict__ b_a1,
                            const float* __restrict__ w_a2, const float* __restrict__ b_a2,
                            const float* __restrict__ w_lat, const float* __restrict__ b_lat,
                            const float* __restrict__ w_sh, const float* __restrict__ b_sh,
                            const float* __restrict__ w_c0, const float* __restrict__ b_c0,
                            float* __restrict__ ws) {
    const int tid = blockIdx.x * blockDim.x + threadIdx.x;
    if (tid < 7680) {
        const int lane = tid & 63;
        const int term = (tid >> 6) & 1;
        const int e    = tid >> 7;         // 0..59
        int u, nt, ks;
        if      (e < 4)  { u = 0; nt = e;            ks = 0; }
        else if (e < 12) { u = 1; nt = (e-4)  >> 1;  ks = (e-4)  & 1; }
        else if (e < 20) { u = 2; nt = (e-12) >> 1;  ks = (e-12) & 1; }
        else if (e < 24) { u = 3; nt = e - 20;       ks = 0; }
        else if (e < 32) { u = 4; nt = (e-24) >> 1;  ks = (e-24) & 1; }
        else if (e < 40) { u = 5; nt = (e-32) >> 1;  ks = (e-32) & 1; }
        else if (e < 48) { u = 6; nt = (e-40) >> 1;  ks = (e-40) & 1; }
        else if (e < 58) { u = 7; nt = (e-48) >> 1;  ks = (e-48) & 1; }
        else             { u = 8; nt = 0;            ks = e - 58; }
        const int jo = nt * 16 + (lane & 15);
        const int quad = lane >> 4;
        f16x8 frag;
#pragma unroll
        for (int j = 0; j < 8; ++j) {
            const int k = ks * 32 + quad * 8 + j;
            float w = 0.0f;
            switch (u) {
                case 0: w = w_b0[jo * 97 + k]; break;
                case 1: w = w_b1[jo * 64 + k]; break;
                case 2: w = w_b2[jo * 64 + k]; break;
                case 3: w = w_a0[jo * 161 + k]; break;
                case 4: w = w_a0[jo * 161 + 97 + k]; break;
                case 5: w = w_a1[jo * 64 + k]; break;
                case 6: w = w_a2[jo * 64 + k]; break;
                case 7: w = (jo < 64) ? w_lat[jo * 64 + k]
                          : ((jo == 64) ? w_sh[k] : 0.0f); break;
                default: w = w_c0[jo * 64 + k]; break;
            }
            const _Float16 hi = (_Float16)w;
            frag[j] = (term == 0) ? hi : (_Float16)((w - (float)hi) * 2048.0f);
        }
        ((f16x8*)ws)[tid] = frag;
    } else if (tid < 8192) {
        const int idx = tid - 7680;
        const int k = idx >> 6, j = idx & 63;
        float s0 = b_b0[j], s1 = b_a0[j];
        for (int i = 0; i < 64; ++i) {
            const float zv = z_slots[k * 64 + i];
            s0 = fmaf(w_b0[j * 97 + 33 + i], zv, s0);
            s1 = fmaf(w_a0[j * 161 + 33 + i], zv, s1);
        }
        ws[WS_ZB0 + idx] = s0;
        ws[WS_ZA0 + idx] = s1;
    } else if (tid < 8544) {
        const int idx = tid - 8192;
        float v;
        if      (idx < 64)  v = b_b1[idx];
        else if (idx < 128) v = b_b2[idx - 64];
        else if (idx < 192) v = b_a1[idx - 128];
        else if (idx < 256) v = b_a2[idx - 192];
        else if (idx < 336) { const int j = idx - 256; v = (j < 64) ? b_lat[j] : ((j == 64) ? b_sh[0] : 0.0f); }
        else                v = b_c0[idx - 336];
        ws[WS_BST + idx] = v;
    } else if (tid < 8672) {
        const int idx = tid - 8544;
        const int j = idx & 63;
        ws[WS_W32 + idx] = (idx < 64) ? w_b0[j * 97 + 32] : w_a0[j * 161 + 32];
    }
}

// ============================ device helpers ============================
__device__ __forceinline__ f16x8 rdfrag(const int* plane, int addr, unsigned sel) {
    const int4 a = *(const int4*)(plane + addr);
    const int4 b = *(const int4*)(plane + addr + 4);
    F4H8 u;
    u.i.x = __builtin_amdgcn_perm(a.y, a.x, sel);
    u.i.y = __builtin_amdgcn_perm(a.w, a.z, sel);
    u.i.z = __builtin_amdgcn_perm(b.y, b.x, sel);
    u.i.w = __builtin_amdgcn_perm(b.w, b.z, sel);
    return u.h;
}

__device__ __forceinline__ f16x8 as_h8(int4 v) { F4H8 u; u.i = v; return u.h; }

__device__ __forceinline__ int pkrtz_i(float a, float b) {
    PK2I u;
    u.h = __builtin_amdgcn_cvt_pkrtz(a, b);
    return u.i;
}

__device__ __forceinline__ void st_hi(int* AHw, int addr, floatx4 v) {
    AHw[addr]       = pkrtz_i(v[0], v[1]);
    AHw[addr + RPS] = pkrtz_i(v[2], v[3]);
}

// hi-only Q store
__device__ __forceinline__ void st_h16(int* QHw, int rp, int halfsel, int feat, float v) {
    ((unsigned short*)QHw)[(rp * QST + feat) * 2 + halfsel] =
        __builtin_bit_cast(unsigned short, (_Float16)v);
}

// dual-tile 64->64 hidden unit, HI-ONLY precision
__device__ __forceinline__ void unitHiDual(int* AH0, int* AH1,
                                           const int4* Bp, int ebase,
                                           const float* __restrict__ bias,
                                           f16x8 th0, f16x8 th1, f16x8 uh0, f16x8 uh1,
                                           int lane, int n, int wrA) {
    int4 B[8];
    floatx4 ac0[4], ac1[4];
#pragma unroll
    for (int nt = 0; nt < 4; ++nt) {
        B[nt*2+0] = Bp[((ebase + nt*2)*2 + 0) * 64 + lane];   // k0 hi
        B[nt*2+1] = Bp[((ebase + nt*2)*2 + 2) * 64 + lane];   // k1 hi
    }
    __builtin_amdgcn_s_setprio(1);
#pragma unroll
    for (int nt = 0; nt < 4; ++nt) {
        const float bv = bias[nt * 16 + n];
        const f16x8 bh0 = as_h8(B[nt*2+0]), bh1 = as_h8(B[nt*2+1]);
        ac0[nt] = (floatx4){bv, bv, bv, bv};
        ac1[nt] = (floatx4){bv, bv, bv, bv};
        ac0[nt] = MFMA(th0, bh0, ac0[nt]); ac0[nt] = MFMA(th1, bh1, ac0[nt]);
        ac1[nt] = MFMA(uh0, bh0, ac1[nt]); ac1[nt] = MFMA(uh1, bh1, ac1[nt]);
    }
    __builtin_amdgcn_s_setprio(0);
#pragma unroll
    for (int nt = 0; nt < 4; ++nt) {
        floatx4 v0, v1;
#pragma unroll
        for (int r = 0; r < 4; ++r) {
            v0[r] = fmaxf(ac0[nt][r], 0.0f);
            v1[r] = fmaxf(ac1[nt][r], 0.0f);
        }
        st_hi(AH0, wrA + nt * 16, v0);
        st_hi(AH1, wrA + nt * 16, v1);
    }
}

// ============================ main kernel ============================
__global__ __launch_bounds__(128, 3)
void fg_kernel(const float* __restrict__ coor_in,
               const float* __restrict__ fg_transform,
               const float* __restrict__ fg_slot_pos,
               const float* __restrict__ w_c1, const float* __restrict__ b_c1,
               const float* __restrict__ ws,
               float* __restrict__ out) {
    __shared__ int LB[2][LROW];
    const int lane = threadIdx.x & 63;
    const int wv   = threadIdx.x >> 6;
    const int tile = blockIdx.x * 2 + wv;     // 32 points per wave (2 tiles of 16)
    const int kk = tile >> 12;                // 4096 tiles per slot
    const int p0 = (tile & 4095) << 5;

    int* AH0 = LB[wv] + L_AH0;
    int* AH1 = LB[wv] + L_AH1;
    float* Q32w  = (float*)(LB[wv] + L_Q32);
    float* OUTSw = (float*)(LB[wv] + L_OUTS);
    float* SIGw  = (float*)(LB[wv] + L_SIG);
    float* CC0   = (float*)(LB[wv] + L_CC0);
    float* CC1   = (float*)(LB[wv] + L_CC1);

    const int* ws_i = (const int*)ws;
    const int4* Bp = (const int4*)ws_i;
    const int n = lane & 15, quad = lane >> 4;
    const unsigned sel = (n & 1) ? 0x07060302u : 0x05040100u;
    const int rdA = (n >> 1) * RPS + quad * 8;
    const int rdQ = (n >> 1) * QST + quad * 8;
    const int wrA = (2 * quad) * RPS + n;

    // ---- phase 0: embedding for both tiles (role = quad, point = n), hi-only Q ----
    // QH planes overlay the heads of AH0/AH1 (Q dies when b0 writes A).
#pragma unroll
    for (int t = 0; t < 2; ++t) {
        int* QHt = LB[wv] + t * 544;
        const int p = n;
        const int role = quad;
        const long idx3 = ((long)kk * PN + p0 + t * 16 + p) * 3;
        const float x = coor_in[idx3 + 0];
        const float y = coor_in[idx3 + 1];
        const float zc = coor_in[idx3 + 2];
        const float T00 = fg_transform[0], T01 = fg_transform[1], T02 = fg_transform[2];
        const float T10 = fg_transform[3], T11 = fg_transform[4], T12 = fg_transform[5];
        const float T20 = fg_transform[6], T21 = fg_transform[7], T22 = fg_transform[8];
        if (role < 3) {
            const float px = fg_slot_pos[kk*3+0], py = fg_slot_pos[kk*3+1], pz = fg_slot_pos[kk*3+2];
            const float rx = x - px, ry = y - py, rz = zc - pz;
            const float cx = T00*rx + T01*ry + T02*rz;
            const float cy = T10*rx + T11*ry + T12*rz;
            const float cz = T20*rx + T21*ry + T22*rz;
            const float c = (role == 0) ? cx : ((role == 1) ? cy : cz);
            const int rp = p >> 1;
            const int hs = p & 1;
            st_h16(QHt, rp, hs, role, c);
            const float rev = c * 0.15915494309189535f;
            const float fr = rev - floorf(rev);
            float s  = __builtin_amdgcn_sinf(fr);
            float co = __builtin_amdgcn_cosf(fr);
#pragma unroll
            for (int l = 0; l < 5; ++l) {
                st_h16(QHt, rp, hs, 3 + 6*l + role, s);
                if (l == 4 && role == 2) {
                    Q32w[t * 16 + p] = co;
                } else {
                    st_h16(QHt, rp, hs, 6 + 6*l + role, co);
                }
                if (l < 4) {
                    const float tt = s * co;
                    const float s2 = s * s;
                    co = fmaf(-2.0f, s2, 1.0f);
                    s  = tt + tt;
                }
            }
        } else {
            const float o0 = T00*x + T01*y + T02*zc;
            const float o1 = T10*x + T11*y + T12*zc;
            const float o2 = T20*x + T21*y + T22*zc;
            const bool outs = (fabsf(o0) > LOC_RATIO) || (fabsf(o1) > LOC_RATIO) || (fabsf(o2) > LOC_RATIO);
            OUTSw[t * 16 + p] = outs ? 1.0f : 0.0f;
        }
    }

    // ---- q hi fragments for both tiles -> registers ----
    const f16x8 qh_0 = rdfrag(LB[wv] + 0,   rdQ, sel);
    const f16x8 qh_1 = rdfrag(LB[wv] + 544, rdQ, sel);

    // ---- b0: q(K=32) hi-only + rank-1 q32; hi-only output ----
    {
        const float* zb0 = ws + WS_ZB0 + kk * 64;
        const float* w32p = ws + WS_W32;
        int4 B[4];
#pragma unroll
        for (int nt = 0; nt < 4; ++nt) {
            B[nt] = Bp[((EB_B0 + nt)*2 + 0) * 64 + lane];
        }
#pragma unroll
        for (int nt = 0; nt < 4; ++nt) {
            const float bv = zb0[nt * 16 + n];
            const float w32 = w32p[nt * 16 + n];
            const f16x8 bh = as_h8(B[nt]);
            floatx4 ac0 = {bv, bv, bv, bv};
            floatx4 ac1 = {bv, bv, bv, bv};
            __builtin_amdgcn_s_setprio(1);
            ac0 = MFMA(qh_0, bh, ac0);
            ac1 = MFMA(qh_1, bh, ac1);
            __builtin_amdgcn_s_setprio(0);
            floatx4 v0, v1;
#pragma unroll
            for (int r = 0; r < 4; ++r) {
                v0[r] = fmaxf(fmaf(w32, Q32w[quad*4+r],    ac0[r]), 0.0f);
                v1[r] = fmaxf(fmaf(w32, Q32w[16+quad*4+r], ac1[r]), 0.0f);
            }
            st_hi(AH0, wrA + nt * 16, v0);
            st_hi(AH1, wrA + nt * 16, v1);
        }
    }

    f16x8 th0, th1, uh0, uh1;
#define RD_H() do { \
        th0 = rdfrag(AH0, rdA, sel);      th1 = rdfrag(AH0, rdA + 32, sel); \
        uh0 = rdfrag(AH1, rdA, sel);      uh1 = rdfrag(AH1, rdA + 32, sel); \
    } while (0)

    RD_H(); unitHiDual(AH0, AH1, Bp, EB_B1, ws + WS_BST + 0,   th0, th1, uh0, uh1, lane, n, wrA);
    RD_H(); unitHiDual(AH0, AH1, Bp, EB_B2, ws + WS_BST + 64,  th0, th1, uh0, uh1, lane, n, wrA);

    // ---- a0: q-part (K=32) hi-only + h-part (K=64) hi-only + rank-1 ----
    RD_H();
    {
        const float* za0 = ws + WS_ZA0 + kk * 64;
        const float* w32p = ws + WS_W32 + 64;
        floatx4 ac0[4], ac1[4];
        int4 B[8];
#pragma unroll
        for (int nt = 0; nt < 4; ++nt) {
            B[nt] = Bp[((EB_A0Q + nt)*2 + 0) * 64 + lane];
        }
        __builtin_amdgcn_s_setprio(1);
#pragma unroll
        for (int nt = 0; nt < 4; ++nt) {
            const float bv = za0[nt * 16 + n];
            const f16x8 bh = as_h8(B[nt]);
            ac0[nt] = (floatx4){bv, bv, bv, bv};
            ac1[nt] = (floatx4){bv, bv, bv, bv};
            ac0[nt] = MFMA(qh_0, bh, ac0[nt]);
            ac1[nt] = MFMA(qh_1, bh, ac1[nt]);
        }
        __builtin_amdgcn_s_setprio(0);
        // h-part: hi-only weights (k0 and k1 hi frags)
#pragma unroll
        for (int nt = 0; nt < 4; ++nt) {
            B[nt*2+0] = Bp[((EB_A0H + nt*2)*2 + 0) * 64 + lane];   // k0 hi
            B[nt*2+1] = Bp[((EB_A0H + nt*2)*2 + 2) * 64 + lane];   // k1 hi
        }
        __builtin_amdgcn_s_setprio(1);
#pragma unroll
        for (int nt = 0; nt < 4; ++nt) {
            const f16x8 bh0 = as_h8(B[nt*2+0]), bh1 = as_h8(B[nt*2+1]);
            ac0[nt] = MFMA(th0, bh0, ac0[nt]); ac0[nt] = MFMA(th1, bh1, ac0[nt]);
            ac1[nt] = MFMA(uh0, bh0, ac1[nt]); ac1[nt] = MFMA(uh1, bh1, ac1[nt]);
        }
        __builtin_amdgcn_s_setprio(0);
#pragma unroll
        for (int nt = 0; nt < 4; ++nt) {
            const float w32 = w32p[nt * 16 + n];
            floatx4 v0, v1;
#pragma unroll
            for (int r = 0; r < 4; ++r) {
                v0[r] = fmaxf(fmaf(w32, Q32w[quad*4+r],    ac0[nt][r]), 0.0f);
                v1[r] = fmaxf(fmaf(w32, Q32w[16+quad*4+r], ac1[nt][r]), 0.0f);
            }
            st_hi(AH0, wrA + nt * 16, v0);
            st_hi(AH1, wrA + nt * 16, v1);
        }
    }

    RD_H(); unitHiDual(AH0, AH1, Bp, EB_A1, ws + WS_BST + 128, th0, th1, uh0, uh1, lane, n, wrA);
    RD_H(); unitHiDual(AH0, AH1, Bp, EB_A2, ws + WS_BST + 192, th0, th1, uh0, uh1, lane, n, wrA);

    // ---- lat (hi-only, no relu) + shape (hi-only -> SIG) ----
    RD_H();
    {
        const float* bias = ws + WS_BST + 256;   // latsh[80]
        int4 B[8];
#pragma unroll
        for (int nt = 0; nt < 4; ++nt) {
            B[nt*2+0] = Bp[((EB_LAT + nt*2)*2 + 0) * 64 + lane];
            B[nt*2+1] = Bp[((EB_LAT + nt*2)*2 + 2) * 64 + lane];
        }
        __builtin_amdgcn_s_setprio(1);
#pragma unroll
        for (int nt = 0; nt < 4; ++nt) {
            const float bv = bias[nt * 16 + n];
            const f16x8 bh0 = as_h8(B[nt*2+0]), bh1 = as_h8(B[nt*2+1]);
            floatx4 a0 = {bv, bv, bv, bv}, a1 = {bv, bv, bv, bv};
            a0 = MFMA(th0, bh0, a0); a0 = MFMA(th1, bh1, a0);
            a1 = MFMA(uh0, bh0, a1); a1 = MFMA(uh1, bh1, a1);
            st_hi(AH0, wrA + nt * 16, a0);
            st_hi(AH1, wrA + nt * 16, a1);
        }
        __builtin_amdgcn_s_setprio(0);
        // shape (sigma) — hi activations, hi weights
        {
            const float bv = bias[64 + n];
            const int e0 = EB_LAT + 8;
            const f16x8 bh0 = as_h8(Bp[(e0*2+0) * 64 + lane]);
            const f16x8 bh1 = as_h8(Bp[(e0*2+2) * 64 + lane]);
            floatx4 a0 = {bv, bv, bv, bv};
            floatx4 a1 = {bv, bv, bv, bv};
            __builtin_amdgcn_s_setprio(1);
            a0 = MFMA(th0, bh0, a0); a0 = MFMA(th1, bh1, a0);
            a1 = MFMA(uh0, bh0, a1); a1 = MFMA(uh1, bh1, a1);
            __builtin_amdgcn_s_setprio(0);
            if (n == 0) {
#pragma unroll
                for (int r = 0; r < 4; ++r) {
                    SIGw[quad * 4 + r]      = a0[r];
                    SIGw[16 + quad * 4 + r] = a1[r];
                }
            }
        }
    }

    // ---- c0: 64 -> 16, hi-only, relu; CC in dedicated region ----
    RD_H();
    {
        const float* bias = ws + WS_BST + 336;
        const float bv = bias[n];
        const f16x8 bh0 = as_h8(Bp[((EB_C0+0)*2+0) * 64 + lane]);
        const f16x8 bh1 = as_h8(Bp[((EB_C0+1)*2+0) * 64 + lane]);
        floatx4 a0 = {bv, bv, bv, bv}, a1 = {bv, bv, bv, bv};
        a0 = MFMA(th0, bh0, a0); a0 = MFMA(th1, bh1, a0);
        a1 = MFMA(uh0, bh0, a1); a1 = MFMA(uh1, bh1, a1);
#pragma unroll
        for (int r = 0; r < 4; ++r) {
            CC0[(quad * 4 + r) * 20 + n] = fmaxf(a0[r], 0.0f);
            CC1[(quad * 4 + r) * 20 + n] = fmaxf(a1[r], 0.0f);
        }
    }

    // ---- heads: lane = p*4 + o, both tiles ----
#pragma unroll
    for (int t = 0; t < 2; ++t) {
        const float* CCt = t ? CC1 : CC0;
        const int p = lane >> 2, o = lane & 3;
        float v;
        if (o < 3) {
            const float* cr = CCt + p * 20;
            float a = b_c1[o];
#pragma unroll
            for (int i = 0; i < 16; ++i) a = fmaf(w_c1[o * 16 + i], cr[i], a);
            // (tanh(a)+1)/2 == sigmoid(2a); native exp+rcp, ~1e-6 abs err vs 2e-2 thr
            const float e = __expf(-2.0f * a);
            v = __builtin_amdgcn_rcpf(1.0f + e);
        } else {
            const float sig = SIGw[t * 16 + p];
            const float outs = OUTSw[t * 16 + p];
            v = (outs > 0.5f) ? 0.0f : fmaxf(sig, 0.0f);
        }
        const long idx = (long)kk * PN + p0 + t * 16 + p;
        out[OFF_UNMASK + (idx << 2) + o] = v;
    }
#undef RD_H
}

// ============================ compose pass ============================
__global__ __launch_bounds__(256)
void compose_kernel(float* __restrict__ out) {
    const int p = blockIdx.x * blockDim.x + threadIdx.x;
    const float4* un = (const float4*)(out + OFF_UNMASK);
    float4 u[KSLOTS];
    float s = 0.0f;
#pragma unroll
    for (int k = 0; k < KSLOTS; ++k) {
        u[k] = un[k * PN + p];
        s += u[k].w;
    }
    // one IEEE division instead of 8 (x*(1/d) vs x/d differs by <=1 ulp; thr 2e-2)
    const float inv = 1.0f / (s + 1e-5f);
    float4* mk = (float4*)(out + OFF_MASKED);
    float* ms = out + OFF_MASKS;
    float4 r = make_float4(0.f, 0.f, 0.f, 0.f);
#pragma unroll
    for (int k = 0; k < KSLOTS; ++k) {
        const float m = u[k].w * inv;
        ms[k * PN + p] = m;
        const float4 v = make_float4(u[k].x * m, u[k].y * m, u[k].z * m, u[k].w * m);
        mk[k * PN + p] = v;
        r.x += v.x; r.y += v.y; r.z += v.z; r.w += v.w;
    }
    ((float4*)(out + OFF_RAWS))[p] = r;
}

// ============================ launch ============================
extern "C" void kernel_launch(void* const* d_in, const int* in_sizes, int n_in,
                              void* d_out, int out_size, void* d_ws, size_t ws_size,
                              hipStream_t stream) {
    const float* coor = (const float*)d_in[0];
    const float* z    = (const float*)d_in[1];
    const float* ft   = (const float*)d_in[2];
    const float* pos  = (const float*)d_in[3];
    const float* w_b0 = (const float*)d_in[4];  const float* b_b0 = (const float*)d_in[5];
    const float* w_b1 = (const float*)d_in[6];  const float* b_b1 = (const float*)d_in[7];
    const float* w_b2 = (const float*)d_in[8];  const float* b_b2 = (const float*)d_in[9];
    const float* w_a0 = (const float*)d_in[10]; const float* b_a0 = (const float*)d_in[11];
    const float* w_a1 = (const float*)d_in[12]; const float* b_a1 = (const float*)d_in[13];
    const float* w_a2 = (const float*)d_in[14]; const float* b_a2 = (const float*)d_in[15];
    const float* w_lat = (const float*)d_in[16]; const float* b_lat = (const float*)d_in[17];
    const float* w_sh  = (const float*)d_in[18]; const float* b_sh  = (const float*)d_in[19];
    const float* w_c0  = (const float*)d_in[20]; const float* b_c0  = (const float*)d_in[21];
    const float* w_c1  = (const float*)d_in[22]; const float* b_c1  = (const float*)d_in[23];
    float* out = (float*)d_out;
    float* ws  = (float*)d_ws;

    hipLaunchKernelGGL(prep_kernel, dim3(34), dim3(256), 0, stream,
                       z,
                       w_b0, b_b0, w_b1, b_b1, w_b2, b_b2,
                       w_a0, b_a0, w_a1, b_a1, w_a2, b_a2,
                       w_lat, b_lat, w_sh, b_sh, w_c0, b_c0, ws);
    hipLaunchKernelGGL(fg_kernel, dim3((KSLOTS * PN / 32) / 2), dim3(128), 0, stream,
                       coor, ft, pos, w_c1, b_c1, ws, out);
    hipLaunchKernelGGL(compose_kernel, dim3(PN / 256), dim3(256), 0, stream, out);
}

// Round 13
// 223.977 us; speedup vs baseline: 1.6945x; 1.0347x over previous
//
#include <hip/hip_runtime.h>
#include <math.h>

#define KSLOTS 8
#define PN     131072
#define LOC_RATIO 0.5714285714285714f
#define INV2048 4.8828125e-4f
#define RPS    68     // A-plane row-pair stride (dwords). MUST stay ≡0 mod 4: 16B-aligned ds_read_b128
                      // (round 11: RPS=70 halved conflicts but split the b128s -> fg 128->270 µs).
#define QST    42     // Q-plane row-pair stride

typedef _Float16 f16x8 __attribute__((ext_vector_type(8)));
typedef __fp16 pk16x2 __attribute__((ext_vector_type(2)));
typedef float floatx4 __attribute__((ext_vector_type(4)));
union F4H8 { int4 i; f16x8 h; };
union PK2I { pk16x2 h; int i; };

#define MFMA(A_,B_,C_) __builtin_amdgcn_mfma_f32_16x16x32_f16(A_,B_,C_,0,0,0)

// ---- B-fragment pair bases ----
#define EB_B0   0
#define EB_B1   4
#define EB_B2   12
#define EB_A0Q  20
#define EB_A0H  24
#define EB_A1   32
#define EB_A2   40
#define EB_LAT  48
#define EB_C0   58
#define WS_ZB0  30720
#define WS_ZA0  31232
#define WS_BST  31744   // b1@0 b2@64 a1@128 a2@192 latsh@256(80) c0@336(16)
#define WS_W32  32096

// ---- output layout (float offsets) ----
#define OFF_RAWS     0
#define OFF_MASKED   524288
#define OFF_UNMASK   4718592
#define OFF_MASKS    8912896

// ---- per-wave LDS map (dwords) ----
// AH0 [0,544), AH1 [544,1088); QH0/QH1 overlay the plane heads (Q dies at b0).
// CC dedicated [1088,1728). scratch at tail. 7296 B/wave, 14592 B/block.
#define L_AH0  0
#define L_AH1  544
#define L_CC0  1088
#define L_CC1  1408
#define L_Q32  1728
#define L_OUTS 1760
#define L_SIG  1792
#define LROW   1824

// ============================ prep kernel ============================
// Round 13: widened parallelism. Weight conversion one element/thread
// (61440 threads, was 7680x8 scattered loads at 34-block occupancy);
// z-fold split 8-ways per output + shfl_xor reduce (range starts at
// thread 61440 = 960 full waves -> 8-lane groups never straddle a wave).
__global__ void prep_kernel(const float* __restrict__ z_slots,
                            const float* __restrict__ w_b0, const float* __restrict__ b_b0,
                            const float* __restrict__ w_b1, const float* __restrict__ b_b1,
                            const float* __restrict__ w_b2, const float* __restrict__ b_b2,
                            const float* __restrict__ w_a0, const float* __restrict__ b_a0,
                            const float* __restrict__ w_a1, const float* __restrict__ b_a1,
                            const float* __restrict__ w_a2, const float* __restrict__ b_a2,
                            const float* __restrict__ w_lat, const float* __restrict__ b_lat,
                            const float* __restrict__ w_sh, const float* __restrict__ b_sh,
                            const float* __restrict__ w_c0, const float* __restrict__ b_c0,
                            float* __restrict__ ws) {
    const int tid = blockIdx.x * blockDim.x + threadIdx.x;
    if (tid < 61440) {
        const int et = tid >> 3;           // original element-thread 0..7679
        const int j  = tid & 7;
        const int lane = et & 63;
        const int term = (et >> 6) & 1;
        const int e    = et >> 7;          // 0..59
        int u, nt, ks;
        if      (e < 4)  { u = 0; nt = e;            ks = 0; }
        else if (e < 12) { u = 1; nt = (e-4)  >> 1;  ks = (e-4)  & 1; }
        else if (e < 20) { u = 2; nt = (e-12) >> 1;  ks = (e-12) & 1; }
        else if (e < 24) { u = 3; nt = e - 20;       ks = 0; }
        else if (e < 32) { u = 4; nt = (e-24) >> 1;  ks = (e-24) & 1; }
        else if (e < 40) { u = 5; nt = (e-32) >> 1;  ks = (e-32) & 1; }
        else if (e < 48) { u = 6; nt = (e-40) >> 1;  ks = (e-40) & 1; }
        else if (e < 58) { u = 7; nt = (e-48) >> 1;  ks = (e-48) & 1; }
        else             { u = 8; nt = 0;            ks = e - 58; }
        const int jo = nt * 16 + (lane & 15);
        const int quad = lane >> 4;
        const int k = ks * 32 + quad * 8 + j;
        float w = 0.0f;
        switch (u) {
            case 0: w = w_b0[jo * 97 + k]; break;
            case 1: w = w_b1[jo * 64 + k]; break;
            case 2: w = w_b2[jo * 64 + k]; break;
            case 3: w = w_a0[jo * 161 + k]; break;
            case 4: w = w_a0[jo * 161 + 97 + k]; break;
            case 5: w = w_a1[jo * 64 + k]; break;
            case 6: w = w_a2[jo * 64 + k]; break;
            case 7: w = (jo < 64) ? w_lat[jo * 64 + k]
                      : ((jo == 64) ? w_sh[k] : 0.0f); break;
            default: w = w_c0[jo * 64 + k]; break;
        }
        const _Float16 hi = (_Float16)w;
        const _Float16 res = (term == 0) ? hi : (_Float16)((w - (float)hi) * 2048.0f);
        ((unsigned short*)ws)[et * 8 + j] = __builtin_bit_cast(unsigned short, res);
    } else if (tid < 65536) {
        const int idx = tid - 61440;       // 0..4095
        const int o = idx >> 3;            // output 0..511
        const int s = idx & 7;             // 8-way split of the 64-dot
        const int k = o >> 6, j = o & 63;
        float p0 = 0.0f, p1 = 0.0f;
#pragma unroll
        for (int t = 0; t < 8; ++t) {
            const int i = s * 8 + t;
            const float zv = z_slots[k * 64 + i];
            p0 = fmaf(w_b0[j * 97 + 33 + i], zv, p0);
            p1 = fmaf(w_a0[j * 161 + 33 + i], zv, p1);
        }
        p0 += __shfl_xor(p0, 1); p1 += __shfl_xor(p1, 1);
        p0 += __shfl_xor(p0, 2); p1 += __shfl_xor(p1, 2);
        p0 += __shfl_xor(p0, 4); p1 += __shfl_xor(p1, 4);
        if (s == 0) {
            ws[WS_ZB0 + o] = p0 + b_b0[j];
            ws[WS_ZA0 + o] = p1 + b_a0[j];
        }
    } else if (tid < 65888) {
        const int idx = tid - 65536;       // 0..351
        float v;
        if      (idx < 64)  v = b_b1[idx];
        else if (idx < 128) v = b_b2[idx - 64];
        else if (idx < 192) v = b_a1[idx - 128];
        else if (idx < 256) v = b_a2[idx - 192];
        else if (idx < 336) { const int j = idx - 256; v = (j < 64) ? b_lat[j] : ((j == 64) ? b_sh[0] : 0.0f); }
        else                v = b_c0[idx - 336];
        ws[WS_BST + idx] = v;
    } else if (tid < 66016) {
        const int idx = tid - 65888;       // 0..127
        const int j = idx & 63;
        ws[WS_W32 + idx] = (idx < 64) ? w_b0[j * 97 + 32] : w_a0[j * 161 + 32];
    }
}

// ============================ device helpers ============================
__device__ __forceinline__ f16x8 rdfrag(const int* plane, int addr, unsigned sel) {
    const int4 a = *(const int4*)(plane + addr);
    const int4 b = *(const int4*)(plane + addr + 4);
    F4H8 u;
    u.i.x = __builtin_amdgcn_perm(a.y, a.x, sel);
    u.i.y = __builtin_amdgcn_perm(a.w, a.z, sel);
    u.i.z = __builtin_amdgcn_perm(b.y, b.x, sel);
    u.i.w = __builtin_amdgcn_perm(b.w, b.z, sel);
    return u.h;
}

__device__ __forceinline__ f16x8 as_h8(int4 v) { F4H8 u; u.i = v; return u.h; }

__device__ __forceinline__ int pkrtz_i(float a, float b) {
    PK2I u;
    u.h = __builtin_amdgcn_cvt_pkrtz(a, b);
    return u.i;
}

__device__ __forceinline__ void st_hi(int* AHw, int addr, floatx4 v) {
    AHw[addr]       = pkrtz_i(v[0], v[1]);
    AHw[addr + RPS] = pkrtz_i(v[2], v[3]);
}

// hi-only Q store
__device__ __forceinline__ void st_h16(int* QHw, int rp, int halfsel, int feat, float v) {
    ((unsigned short*)QHw)[(rp * QST + feat) * 2 + halfsel] =
        __builtin_bit_cast(unsigned short, (_Float16)v);
}

// dual-tile 64->64 hidden unit, HI-ONLY precision
__device__ __forceinline__ void unitHiDual(int* AH0, int* AH1,
                                           const int4* Bp, int ebase,
                                           const float* __restrict__ bias,
                                           f16x8 th0, f16x8 th1, f16x8 uh0, f16x8 uh1,
                                           int lane, int n, int wrA) {
    int4 B[8];
    floatx4 ac0[4], ac1[4];
#pragma unroll
    for (int nt = 0; nt < 4; ++nt) {
        B[nt*2+0] = Bp[((ebase + nt*2)*2 + 0) * 64 + lane];   // k0 hi
        B[nt*2+1] = Bp[((ebase + nt*2)*2 + 2) * 64 + lane];   // k1 hi
    }
    __builtin_amdgcn_s_setprio(1);
#pragma unroll
    for (int nt = 0; nt < 4; ++nt) {
        const float bv = bias[nt * 16 + n];
        const f16x8 bh0 = as_h8(B[nt*2+0]), bh1 = as_h8(B[nt*2+1]);
        ac0[nt] = (floatx4){bv, bv, bv, bv};
        ac1[nt] = (floatx4){bv, bv, bv, bv};
        ac0[nt] = MFMA(th0, bh0, ac0[nt]); ac0[nt] = MFMA(th1, bh1, ac0[nt]);
        ac1[nt] = MFMA(uh0, bh0, ac1[nt]); ac1[nt] = MFMA(uh1, bh1, ac1[nt]);
    }
    __builtin_amdgcn_s_setprio(0);
#pragma unroll
    for (int nt = 0; nt < 4; ++nt) {
        floatx4 v0, v1;
#pragma unroll
        for (int r = 0; r < 4; ++r) {
            v0[r] = fmaxf(ac0[nt][r], 0.0f);
            v1[r] = fmaxf(ac1[nt][r], 0.0f);
        }
        st_hi(AH0, wrA + nt * 16, v0);
        st_hi(AH1, wrA + nt * 16, v1);
    }
}

// ============================ main kernel ============================
__global__ __launch_bounds__(128, 3)
void fg_kernel(const float* __restrict__ coor_in,
               const float* __restrict__ fg_transform,
               const float* __restrict__ fg_slot_pos,
               const float* __restrict__ w_c1, const float* __restrict__ b_c1,
               const float* __restrict__ ws,
               float* __restrict__ out) {
    __shared__ int LB[2][LROW];
    const int lane = threadIdx.x & 63;
    const int wv   = threadIdx.x >> 6;
    const int tile = blockIdx.x * 2 + wv;     // 32 points per wave (2 tiles of 16)
    const int kk = tile >> 12;                // 4096 tiles per slot
    const int p0 = (tile & 4095) << 5;

    int* AH0 = LB[wv] + L_AH0;
    int* AH1 = LB[wv] + L_AH1;
    float* Q32w  = (float*)(LB[wv] + L_Q32);
    float* OUTSw = (float*)(LB[wv] + L_OUTS);
    float* SIGw  = (float*)(LB[wv] + L_SIG);
    float* CC0   = (float*)(LB[wv] + L_CC0);
    float* CC1   = (float*)(LB[wv] + L_CC1);

    const int* ws_i = (const int*)ws;
    const int4* Bp = (const int4*)ws_i;
    const int n = lane & 15, quad = lane >> 4;
    const unsigned sel = (n & 1) ? 0x07060302u : 0x05040100u;
    const int rdA = (n >> 1) * RPS + quad * 8;
    const int rdQ = (n >> 1) * QST + quad * 8;
    const int wrA = (2 * quad) * RPS + n;

    // ---- phase 0: embedding for both tiles (role = quad, point = n), hi-only Q ----
    // QH planes overlay the heads of AH0/AH1 (Q dies when b0 writes A).
#pragma unroll
    for (int t = 0; t < 2; ++t) {
        int* QHt = LB[wv] + t * 544;
        const int p = n;
        const int role = quad;
        const long idx3 = ((long)kk * PN + p0 + t * 16 + p) * 3;
        const float x = coor_in[idx3 + 0];
        const float y = coor_in[idx3 + 1];
        const float zc = coor_in[idx3 + 2];
        const float T00 = fg_transform[0], T01 = fg_transform[1], T02 = fg_transform[2];
        const float T10 = fg_transform[3], T11 = fg_transform[4], T12 = fg_transform[5];
        const float T20 = fg_transform[6], T21 = fg_transform[7], T22 = fg_transform[8];
        if (role < 3) {
            const float px = fg_slot_pos[kk*3+0], py = fg_slot_pos[kk*3+1], pz = fg_slot_pos[kk*3+2];
            const float rx = x - px, ry = y - py, rz = zc - pz;
            const float cx = T00*rx + T01*ry + T02*rz;
            const float cy = T10*rx + T11*ry + T12*rz;
            const float cz = T20*rx + T21*ry + T22*rz;
            const float c = (role == 0) ? cx : ((role == 1) ? cy : cz);
            const int rp = p >> 1;
            const int hs = p & 1;
            st_h16(QHt, rp, hs, role, c);
            const float rev = c * 0.15915494309189535f;
            const float fr = rev - floorf(rev);
            float s  = __builtin_amdgcn_sinf(fr);
            float co = __builtin_amdgcn_cosf(fr);
#pragma unroll
            for (int l = 0; l < 5; ++l) {
                st_h16(QHt, rp, hs, 3 + 6*l + role, s);
                if (l == 4 && role == 2) {
                    Q32w[t * 16 + p] = co;
                } else {
                    st_h16(QHt, rp, hs, 6 + 6*l + role, co);
                }
                if (l < 4) {
                    const float tt = s * co;
                    const float s2 = s * s;
                    co = fmaf(-2.0f, s2, 1.0f);
                    s  = tt + tt;
                }
            }
        } else {
            const float o0 = T00*x + T01*y + T02*zc;
            const float o1 = T10*x + T11*y + T12*zc;
            const float o2 = T20*x + T21*y + T22*zc;
            const bool outs = (fabsf(o0) > LOC_RATIO) || (fabsf(o1) > LOC_RATIO) || (fabsf(o2) > LOC_RATIO);
            OUTSw[t * 16 + p] = outs ? 1.0f : 0.0f;
        }
    }

    // ---- q hi fragments for both tiles -> registers ----
    const f16x8 qh_0 = rdfrag(LB[wv] + 0,   rdQ, sel);
    const f16x8 qh_1 = rdfrag(LB[wv] + 544, rdQ, sel);

    // ---- b0: q(K=32) hi-only + rank-1 q32; hi-only output ----
    {
        const float* zb0 = ws + WS_ZB0 + kk * 64;
        const float* w32p = ws + WS_W32;
        int4 B[4];
#pragma unroll
        for (int nt = 0; nt < 4; ++nt) {
            B[nt] = Bp[((EB_B0 + nt)*2 + 0) * 64 + lane];
        }
#pragma unroll
        for (int nt = 0; nt < 4; ++nt) {
            const float bv = zb0[nt * 16 + n];
            const float w32 = w32p[nt * 16 + n];
            const f16x8 bh = as_h8(B[nt]);
            floatx4 ac0 = {bv, bv, bv, bv};
            floatx4 ac1 = {bv, bv, bv, bv};
            __builtin_amdgcn_s_setprio(1);
            ac0 = MFMA(qh_0, bh, ac0);
            ac1 = MFMA(qh_1, bh, ac1);
            __builtin_amdgcn_s_setprio(0);
            floatx4 v0, v1;
#pragma unroll
            for (int r = 0; r < 4; ++r) {
                v0[r] = fmaxf(fmaf(w32, Q32w[quad*4+r],    ac0[r]), 0.0f);
                v1[r] = fmaxf(fmaf(w32, Q32w[16+quad*4+r], ac1[r]), 0.0f);
            }
            st_hi(AH0, wrA + nt * 16, v0);
            st_hi(AH1, wrA + nt * 16, v1);
        }
    }

    f16x8 th0, th1, uh0, uh1;
#define RD_H() do { \
        th0 = rdfrag(AH0, rdA, sel);      th1 = rdfrag(AH0, rdA + 32, sel); \
        uh0 = rdfrag(AH1, rdA, sel);      uh1 = rdfrag(AH1, rdA + 32, sel); \
    } while (0)

    RD_H(); unitHiDual(AH0, AH1, Bp, EB_B1, ws + WS_BST + 0,   th0, th1, uh0, uh1, lane, n, wrA);
    RD_H(); unitHiDual(AH0, AH1, Bp, EB_B2, ws + WS_BST + 64,  th0, th1, uh0, uh1, lane, n, wrA);

    // ---- a0: q-part (K=32) hi-only + h-part (K=64) hi-only + rank-1 ----
    RD_H();
    {
        const float* za0 = ws + WS_ZA0 + kk * 64;
        const float* w32p = ws + WS_W32 + 64;
        floatx4 ac0[4], ac1[4];
        int4 B[8];
#pragma unroll
        for (int nt = 0; nt < 4; ++nt) {
            B[nt] = Bp[((EB_A0Q + nt)*2 + 0) * 64 + lane];
        }
        __builtin_amdgcn_s_setprio(1);
#pragma unroll
        for (int nt = 0; nt < 4; ++nt) {
            const float bv = za0[nt * 16 + n];
            const f16x8 bh = as_h8(B[nt]);
            ac0[nt] = (floatx4){bv, bv, bv, bv};
            ac1[nt] = (floatx4){bv, bv, bv, bv};
            ac0[nt] = MFMA(qh_0, bh, ac0[nt]);
            ac1[nt] = MFMA(qh_1, bh, ac1[nt]);
        }
        __builtin_amdgcn_s_setprio(0);
        // h-part: hi-only weights (k0 and k1 hi frags)
#pragma unroll
        for (int nt = 0; nt < 4; ++nt) {
            B[nt*2+0] = Bp[((EB_A0H + nt*2)*2 + 0) * 64 + lane];   // k0 hi
            B[nt*2+1] = Bp[((EB_A0H + nt*2)*2 + 2) * 64 + lane];   // k1 hi
        }
        __builtin_amdgcn_s_setprio(1);
#pragma unroll
        for (int nt = 0; nt < 4; ++nt) {
            const f16x8 bh0 = as_h8(B[nt*2+0]), bh1 = as_h8(B[nt*2+1]);
            ac0[nt] = MFMA(th0, bh0, ac0[nt]); ac0[nt] = MFMA(th1, bh1, ac0[nt]);
            ac1[nt] = MFMA(uh0, bh0, ac1[nt]); ac1[nt] = MFMA(uh1, bh1, ac1[nt]);
        }
        __builtin_amdgcn_s_setprio(0);
#pragma unroll
        for (int nt = 0; nt < 4; ++nt) {
            const float w32 = w32p[nt * 16 + n];
            floatx4 v0, v1;
#pragma unroll
            for (int r = 0; r < 4; ++r) {
                v0[r] = fmaxf(fmaf(w32, Q32w[quad*4+r],    ac0[nt][r]), 0.0f);
                v1[r] = fmaxf(fmaf(w32, Q32w[16+quad*4+r], ac1[nt][r]), 0.0f);
            }
            st_hi(AH0, wrA + nt * 16, v0);
            st_hi(AH1, wrA + nt * 16, v1);
        }
    }

    RD_H(); unitHiDual(AH0, AH1, Bp, EB_A1, ws + WS_BST + 128, th0, th1, uh0, uh1, lane, n, wrA);
    RD_H(); unitHiDual(AH0, AH1, Bp, EB_A2, ws + WS_BST + 192, th0, th1, uh0, uh1, lane, n, wrA);

    // ---- lat (hi-only, no relu) + shape (hi-only -> SIG) ----
    RD_H();
    {
        const float* bias = ws + WS_BST + 256;   // latsh[80]
        int4 B[8];
#pragma unroll
        for (int nt = 0; nt < 4; ++nt) {
            B[nt*2+0] = Bp[((EB_LAT + nt*2)*2 + 0) * 64 + lane];
            B[nt*2+1] = Bp[((EB_LAT + nt*2)*2 + 2) * 64 + lane];
        }
        __builtin_amdgcn_s_setprio(1);
#pragma unroll
        for (int nt = 0; nt < 4; ++nt) {
            const float bv = bias[nt * 16 + n];
            const f16x8 bh0 = as_h8(B[nt*2+0]), bh1 = as_h8(B[nt*2+1]);
            floatx4 a0 = {bv, bv, bv, bv}, a1 = {bv, bv, bv, bv};
            a0 = MFMA(th0, bh0, a0); a0 = MFMA(th1, bh1, a0);
            a1 = MFMA(uh0, bh0, a1); a1 = MFMA(uh1, bh1, a1);
            st_hi(AH0, wrA + nt * 16, a0);
            st_hi(AH1, wrA + nt * 16, a1);
        }
        __builtin_amdgcn_s_setprio(0);
        // shape (sigma) — hi activations, hi weights
        {
            const float bv = bias[64 + n];
            const int e0 = EB_LAT + 8;
            const f16x8 bh0 = as_h8(Bp[(e0*2+0) * 64 + lane]);
            const f16x8 bh1 = as_h8(Bp[(e0*2+2) * 64 + lane]);
            floatx4 a0 = {bv, bv, bv, bv};
            floatx4 a1 = {bv, bv, bv, bv};
            __builtin_amdgcn_s_setprio(1);
            a0 = MFMA(th0, bh0, a0); a0 = MFMA(th1, bh1, a0);
            a1 = MFMA(uh0, bh0, a1); a1 = MFMA(uh1, bh1, a1);
            __builtin_amdgcn_s_setprio(0);
            if (n == 0) {
#pragma unroll
                for (int r = 0; r < 4; ++r) {
                    SIGw[quad * 4 + r]      = a0[r];
                    SIGw[16 + quad * 4 + r] = a1[r];
                }
            }
        }
    }

    // ---- c0: 64 -> 16, hi-only, relu; CC in dedicated region ----
    RD_H();
    {
        const float* bias = ws + WS_BST + 336;
        const float bv = bias[n];
        const f16x8 bh0 = as_h8(Bp[((EB_C0+0)*2+0) * 64 + lane]);
        const f16x8 bh1 = as_h8(Bp[((EB_C0+1)*2+0) * 64 + lane]);
        floatx4 a0 = {bv, bv, bv, bv}, a1 = {bv, bv, bv, bv};
        a0 = MFMA(th0, bh0, a0); a0 = MFMA(th1, bh1, a0);
        a1 = MFMA(uh0, bh0, a1); a1 = MFMA(uh1, bh1, a1);
#pragma unroll
        for (int r = 0; r < 4; ++r) {
            CC0[(quad * 4 + r) * 20 + n] = fmaxf(a0[r], 0.0f);
            CC1[(quad * 4 + r) * 20 + n] = fmaxf(a1[r], 0.0f);
        }
    }

    // ---- heads: lane = p*4 + o, both tiles ----
#pragma unroll
    for (int t = 0; t < 2; ++t) {
        const float* CCt = t ? CC1 : CC0;
        const int p = lane >> 2, o = lane & 3;
        float v;
        if (o < 3) {
            const float* cr = CCt + p * 20;
            float a = b_c1[o];
#pragma unroll
            for (int i = 0; i < 16; ++i) a = fmaf(w_c1[o * 16 + i], cr[i], a);
            // (tanh(a)+1)/2 == sigmoid(2a); native exp+rcp, ~1e-6 abs err vs 2e-2 thr
            const float e = __expf(-2.0f * a);
            v = __builtin_amdgcn_rcpf(1.0f + e);
        } else {
            const float sig = SIGw[t * 16 + p];
            const float outs = OUTSw[t * 16 + p];
            v = (outs > 0.5f) ? 0.0f : fmaxf(sig, 0.0f);
        }
        const long idx = (long)kk * PN + p0 + t * 16 + p;
        out[OFF_UNMASK + (idx << 2) + o] = v;
    }
#undef RD_H
}

// ============================ compose pass ============================
__global__ __launch_bounds__(256)
void compose_kernel(float* __restrict__ out) {
    const int p = blockIdx.x * blockDim.x + threadIdx.x;
    const float4* un = (const float4*)(out + OFF_UNMASK);
    float4 u[KSLOTS];
    float s = 0.0f;
#pragma unroll
    for (int k = 0; k < KSLOTS; ++k) {
        u[k] = un[k * PN + p];
        s += u[k].w;
    }
    // one IEEE division instead of 8 (x*(1/d) vs x/d differs by <=1 ulp; thr 2e-2)
    const float inv = 1.0f / (s + 1e-5f);
    float4* mk = (float4*)(out + OFF_MASKED);
    float* ms = out + OFF_MASKS;
    float4 r = make_float4(0.f, 0.f, 0.f, 0.f);
#pragma unroll
    for (int k = 0; k < KSLOTS; ++k) {
        const float m = u[k].w * inv;
        ms[k * PN + p] = m;
        const float4 v = make_float4(u[k].x * m, u[k].y * m, u[k].z * m, u[k].w * m);
        mk[k * PN + p] = v;
        r.x += v.x; r.y += v.y; r.z += v.z; r.w += v.w;
    }
    ((float4*)(out + OFF_RAWS))[p] = r;
}

// ============================ launch ============================
extern "C" void kernel_launch(void* const* d_in, const int* in_sizes, int n_in,
                              void* d_out, int out_size, void* d_ws, size_t ws_size,
                              hipStream_t stream) {
    const float* coor = (const float*)d_in[0];
    const float* z    = (const float*)d_in[1];
    const float* ft   = (const float*)d_in[2];
    const float* pos  = (const float*)d_in[3];
    const float* w_b0 = (const float*)d_in[4];  const float* b_b0 = (const float*)d_in[5];
    const float* w_b1 = (const float*)d_in[6];  const float* b_b1 = (const float*)d_in[7];
    const float* w_b2 = (const float*)d_in[8];  const float* b_b2 = (const float*)d_in[9];
    const float* w_a0 = (const float*)d_in[10]; const float* b_a0 = (const float*)d_in[11];
    const float* w_a1 = (const float*)d_in[12]; const float* b_a1 = (const float*)d_in[13];
    const float* w_a2 = (const float*)d_in[14]; const float* b_a2 = (const float*)d_in[15];
    const float* w_lat = (const float*)d_in[16]; const float* b_lat = (const float*)d_in[17];
    const float* w_sh  = (const float*)d_in[18]; const float* b_sh  = (const float*)d_in[19];
    const float* w_c0  = (const float*)d_in[20]; const float* b_c0  = (const float*)d_in[21];
    const float* w_c1  = (const float*)d_in[22]; const float* b_c1  = (const float*)d_in[23];
    float* out = (float*)d_out;
    float* ws  = (float*)d_ws;

    hipLaunchKernelGGL(prep_kernel, dim3(258), dim3(256), 0, stream,
                       z,
                       w_b0, b_b0, w_b1, b_b1, w_b2, b_b2,
                       w_a0, b_a0, w_a1, b_a1, w_a2, b_a2,
                       w_lat, b_lat, w_sh, b_sh, w_c0, b_c0, ws);
    hipLaunchKernelGGL(fg_kernel, dim3((KSLOTS * PN / 32) / 2), dim3(128), 0, stream,
                       coor, ft, pos, w_c1, b_c1, ws, out);
    hipLaunchKernelGGL(compose_kernel, dim3(PN / 256), dim3(256), 0, stream, out);
}